// Round 1
// baseline (321.392 us; speedup 1.0000x reference)
//
#include <hip/hip_runtime.h>
#include <math.h>

// Problem constants
#define S_LEN 2048
#define BATCH 4
#define DMODEL 1024
#define HDIM 64
#define NROWS (BATCH * S_LEN)   // 8192 flattened (b,s) rows

// ---------------------------------------------------------------------------
// Kernel 1a: generic skinny GEMM  C[M,64] = A[M,1024] @ B[1024,64] (+bias)
// Used for: W_eff = W @ w_h   (M=1024, grid.y selects q/k/v)
//           ph    = x @ W_eff (M=8192, grid.y selects q/k/v)
// Block: 256 threads, 64-row tile, k-tiled by 64, 4x4 register blocking.
// ---------------------------------------------------------------------------
__global__ __launch_bounds__(256) void gemm_n64_k1024(
    const float* __restrict__ A0, const float* __restrict__ A1, const float* __restrict__ A2,
    const float* __restrict__ B0, const float* __restrict__ B1, const float* __restrict__ B2,
    const float* __restrict__ bias0, const float* __restrict__ bias1, const float* __restrict__ bias2,
    float* __restrict__ C0, float* __restrict__ C1, float* __restrict__ C2)
{
    const int z = blockIdx.y;
    const float* A    = (z == 0) ? A0 : (z == 1) ? A1 : A2;
    const float* B    = (z == 0) ? B0 : (z == 1) ? B1 : B2;
    const float* bias = (z == 0) ? bias0 : (z == 1) ? bias1 : bias2;
    float* C          = (z == 0) ? C0 : (z == 1) ? C1 : C2;

    __shared__ float As[64][65];   // +1 pad: rows read at stride -> spread banks
    __shared__ float Bs[64][64];   // read along rows: 2-way max, free

    const int t  = threadIdx.x;
    const int tr = t >> 4;         // 0..15 -> rows 4*tr..4*tr+3
    const int tc = t & 15;         // 0..15 -> cols 4*tc..4*tc+3
    const int r0 = blockIdx.x * 64;

    float acc[4][4] = {};

    for (int k0 = 0; k0 < 1024; k0 += 64) {
        __syncthreads();
        // stage A tile: 64 rows x 64 k  (coalesced float4)
        #pragma unroll
        for (int q = 0; q < 4; ++q) {
            int fid = t * 4 + q;              // 0..1023 float4 slots
            int row = fid >> 4;
            int c4  = (fid & 15) << 2;
            float4 v = *reinterpret_cast<const float4*>(
                A + (size_t)(r0 + row) * 1024 + k0 + c4);
            As[row][c4 + 0] = v.x; As[row][c4 + 1] = v.y;
            As[row][c4 + 2] = v.z; As[row][c4 + 3] = v.w;
        }
        // stage B tile: 64 k x 64 n
        #pragma unroll
        for (int q = 0; q < 4; ++q) {
            int fid = t * 4 + q;
            int row = fid >> 4;
            int c4  = (fid & 15) << 2;
            float4 v = *reinterpret_cast<const float4*>(
                B + (size_t)(k0 + row) * 64 + c4);
            *reinterpret_cast<float4*>(&Bs[row][c4]) = v;
        }
        __syncthreads();

        #pragma unroll 4
        for (int kk = 0; kk < 64; ++kk) {
            float a[4], bb[4];
            #pragma unroll
            for (int i = 0; i < 4; ++i) a[i]  = As[4 * tr + i][kk];
            #pragma unroll
            for (int j = 0; j < 4; ++j) bb[j] = Bs[kk][4 * tc + j];
            #pragma unroll
            for (int i = 0; i < 4; ++i)
                #pragma unroll
                for (int j = 0; j < 4; ++j)
                    acc[i][j] += a[i] * bb[j];
        }
    }

    #pragma unroll
    for (int i = 0; i < 4; ++i)
        #pragma unroll
        for (int j = 0; j < 4; ++j) {
            float v = acc[i][j];
            if (bias) v += bias[4 * tc + j];
            C[(size_t)(r0 + 4 * tr + i) * 64 + 4 * tc + j] = v;
        }
}

// ---------------------------------------------------------------------------
// Kernel 1b: Wo_eff[j,e] = sum_h Wo[h*64+j, e]   (64 x 1024)
// ---------------------------------------------------------------------------
__global__ __launch_bounds__(256) void fold_wo(const float* __restrict__ Wo,
                                               float* __restrict__ Woeff)
{
    int idx = blockIdx.x * 256 + threadIdx.x;   // 0..65535
    int j = idx >> 10;
    int e = idx & 1023;
    float s = 0.f;
    #pragma unroll
    for (int h = 0; h < 16; ++h)
        s += Wo[(size_t)((h << 6) + j) * 1024 + e];
    Woeff[idx] = s;
}

// ---------------------------------------------------------------------------
// Kernel 2: causal flash attention, single head dim 64, f32.
// Grid: (S/32, B). Block 256 threads. 32 q-rows per block.
// Thread (tr=t>>4, tc=t&15): rows 2*tr+i (i<2), cols/kv 4*tc+j (j<4).
// ---------------------------------------------------------------------------
__global__ __launch_bounds__(256) void flash_attn(const float* __restrict__ ph,
                                                  float* __restrict__ oh)
{
    const int b  = blockIdx.y;
    const int r0 = blockIdx.x * 32;
    const size_t PHS = (size_t)BATCH * S_LEN * HDIM;
    const float* qh = ph + (size_t)b * S_LEN * HDIM;
    const float* kh = qh + PHS;
    const float* vh = qh + 2 * PHS;

    __shared__ float Qs[32][65];
    __shared__ float Ks[64][65];
    __shared__ float Vs[64][64];
    __shared__ float Ps[32][65];

    const int t  = threadIdx.x;
    const int tr = t >> 4;
    const int tc = t & 15;

    // stage Q tile (32 x 64)
    #pragma unroll
    for (int q = 0; q < 2; ++q) {
        int fid = t * 2 + q;              // 0..511
        int row = fid >> 4;
        int c4  = (fid & 15) << 2;
        float4 v = *reinterpret_cast<const float4*>(
            qh + (size_t)(r0 + row) * HDIM + c4);
        Qs[row][c4 + 0] = v.x; Qs[row][c4 + 1] = v.y;
        Qs[row][c4 + 2] = v.z; Qs[row][c4 + 3] = v.w;
    }

    float O[2][4] = {};
    float m[2] = {-INFINITY, -INFINITY};
    float l[2] = {0.f, 0.f};

    const int ntiles = r0 / 64 + 1;
    for (int tt = 0; tt < ntiles; ++tt) {
        const int t0 = tt * 64;
        __syncthreads();   // prior-iteration LDS reads done before overwrite
        #pragma unroll
        for (int q = 0; q < 4; ++q) {
            int fid = t * 4 + q;          // 0..1023
            int row = fid >> 4;
            int c4  = (fid & 15) << 2;
            float4 kv = *reinterpret_cast<const float4*>(
                kh + (size_t)(t0 + row) * HDIM + c4);
            Ks[row][c4 + 0] = kv.x; Ks[row][c4 + 1] = kv.y;
            Ks[row][c4 + 2] = kv.z; Ks[row][c4 + 3] = kv.w;
            float4 vv = *reinterpret_cast<const float4*>(
                vh + (size_t)(t0 + row) * HDIM + c4);
            *reinterpret_cast<float4*>(&Vs[row][c4]) = vv;
        }
        __syncthreads();

        // S = Q K^T / 8
        float s[2][4] = {};
        #pragma unroll 4
        for (int kk = 0; kk < 64; ++kk) {
            float qv[2], kv[4];
            #pragma unroll
            for (int i = 0; i < 2; ++i) qv[i] = Qs[2 * tr + i][kk];
            #pragma unroll
            for (int j = 0; j < 4; ++j) kv[j] = Ks[4 * tc + j][kk];
            #pragma unroll
            for (int i = 0; i < 2; ++i)
                #pragma unroll
                for (int j = 0; j < 4; ++j)
                    s[i][j] += qv[i] * kv[j];
        }
        #pragma unroll
        for (int i = 0; i < 2; ++i)
            #pragma unroll
            for (int j = 0; j < 4; ++j) {
                s[i][j] *= 0.125f;
                int col = t0 + 4 * tc + j;
                int row = r0 + 2 * tr + i;
                if (col > row) s[i][j] = -1e30f;  // masked -> exp underflows to 0
            }

        // online softmax (row shared by the 16 lanes with equal tr -> shfl_xor<16)
        #pragma unroll
        for (int i = 0; i < 2; ++i) {
            float rm = fmaxf(fmaxf(s[i][0], s[i][1]), fmaxf(s[i][2], s[i][3]));
            rm = fmaxf(rm, __shfl_xor(rm, 1));
            rm = fmaxf(rm, __shfl_xor(rm, 2));
            rm = fmaxf(rm, __shfl_xor(rm, 4));
            rm = fmaxf(rm, __shfl_xor(rm, 8));
            float mn = fmaxf(m[i], rm);
            float sc = expf(m[i] - mn);          // m=-inf first tile -> 0
            float p[4];
            float rs = 0.f;
            #pragma unroll
            for (int j = 0; j < 4; ++j) { p[j] = expf(s[i][j] - mn); rs += p[j]; }
            rs += __shfl_xor(rs, 1);
            rs += __shfl_xor(rs, 2);
            rs += __shfl_xor(rs, 4);
            rs += __shfl_xor(rs, 8);
            l[i] = l[i] * sc + rs;
            m[i] = mn;
            #pragma unroll
            for (int j = 0; j < 4; ++j) O[i][j] *= sc;
            #pragma unroll
            for (int j = 0; j < 4; ++j) Ps[2 * tr + i][4 * tc + j] = p[j];
        }
        __syncthreads();

        // O += P V
        #pragma unroll 4
        for (int kk = 0; kk < 64; ++kk) {
            float pv[2], vv[4];
            #pragma unroll
            for (int i = 0; i < 2; ++i) pv[i] = Ps[2 * tr + i][kk];
            #pragma unroll
            for (int j = 0; j < 4; ++j) vv[j] = Vs[kk][4 * tc + j];
            #pragma unroll
            for (int i = 0; i < 2; ++i)
                #pragma unroll
                for (int j = 0; j < 4; ++j)
                    O[i][j] += pv[i] * vv[j];
        }
    }

    #pragma unroll
    for (int i = 0; i < 2; ++i) {
        float inv = 1.f / l[i];
        #pragma unroll
        for (int j = 0; j < 4; ++j)
            oh[(size_t)b * S_LEN * HDIM + (size_t)(r0 + 2 * tr + i) * HDIM +
               4 * tc + j] = O[i][j] * inv;
    }
}

// ---------------------------------------------------------------------------
// Kernel 3: out[8192,1024] = oh[8192,64] @ Woeff[64,1024]
// Grid: (8192/32, 1024/128). Block 256. Thread cols are tc+32*j (stride-32,
// so the Ws row read is conflict-free: 32 consecutive addrs, 2-way broadcast).
// ---------------------------------------------------------------------------
__global__ __launch_bounds__(256) void epilogue(const float* __restrict__ oh,
                                                const float* __restrict__ Woeff,
                                                float* __restrict__ out)
{
    const int r0 = blockIdx.x * 32;
    const int c0 = blockIdx.y * 128;
    const int t  = threadIdx.x;
    const int tr = t >> 5;   // 0..7 -> rows 4*tr+i
    const int tc = t & 31;   // cols tc + 32*j

    __shared__ float OHs[32][65];
    __shared__ float Ws[64][128];

    #pragma unroll
    for (int q = 0; q < 2; ++q) {
        int fid = t * 2 + q;              // 0..511
        int row = fid >> 4;
        int c4  = (fid & 15) << 2;
        float4 v = *reinterpret_cast<const float4*>(
            oh + (size_t)(r0 + row) * HDIM + c4);
        OHs[row][c4 + 0] = v.x; OHs[row][c4 + 1] = v.y;
        OHs[row][c4 + 2] = v.z; OHs[row][c4 + 3] = v.w;
    }
    #pragma unroll
    for (int q = 0; q < 8; ++q) {
        int fid = t * 8 + q;              // 0..2047 float4 slots
        int row = fid >> 5;               // 0..63
        int c4  = (fid & 31) << 2;        // 0..124
        float4 v = *reinterpret_cast<const float4*>(
            Woeff + (size_t)row * 1024 + c0 + c4);
        *reinterpret_cast<float4*>(&Ws[row][c4]) = v;
    }
    __syncthreads();

    float acc[4][4] = {};
    #pragma unroll 4
    for (int kk = 0; kk < 64; ++kk) {
        float a[4], w[4];
        #pragma unroll
        for (int i = 0; i < 4; ++i) a[i] = OHs[4 * tr + i][kk];
        #pragma unroll
        for (int j = 0; j < 4; ++j) w[j] = Ws[kk][tc + 32 * j];
        #pragma unroll
        for (int i = 0; i < 4; ++i)
            #pragma unroll
            for (int j = 0; j < 4; ++j)
                acc[i][j] += a[i] * w[j];
    }

    #pragma unroll
    for (int i = 0; i < 4; ++i)
        #pragma unroll
        for (int j = 0; j < 4; ++j)
            out[(size_t)(r0 + 4 * tr + i) * 1024 + c0 + tc + 32 * j] = acc[i][j];
}

// ---------------------------------------------------------------------------
extern "C" void kernel_launch(void* const* d_in, const int* in_sizes, int n_in,
                              void* d_out, int out_size, void* d_ws, size_t ws_size,
                              hipStream_t stream)
{
    const float* query = (const float*)d_in[0];
    const float* key   = (const float*)d_in[1];
    const float* value = (const float*)d_in[2];
    // d_in[3] = mask (unused: causal structure is hard-coded)
    const float* Wq   = (const float*)d_in[4];
    const float* Wk   = (const float*)d_in[5];
    const float* Wv   = (const float*)d_in[6];
    const float* wq_h = (const float*)d_in[7];
    const float* bq_h = (const float*)d_in[8];
    const float* wk_h = (const float*)d_in[9];
    const float* bk_h = (const float*)d_in[10];
    const float* wv_h = (const float*)d_in[11];
    const float* bv_h = (const float*)d_in[12];
    const float* Wo   = (const float*)d_in[13];
    float* out = (float*)d_out;

    // workspace layout (floats): 9.44 MB total
    float* ws    = (float*)d_ws;
    float* Weff0 = ws;                  // 1024*64
    float* Weff1 = ws + 65536;
    float* Weff2 = ws + 131072;
    float* Woeff = ws + 196608;         // 64*1024
    float* ph    = ws + 262144;         // 3 * 8192*64 (qh,kh,vh)
    float* oh    = ws + 1835008;        // 8192*64

    // 1) effective weights: W*_eff = W* @ w*_h  (collapses the 1024x1024 GEMMs)
    gemm_n64_k1024<<<dim3(16, 3), 256, 0, stream>>>(
        Wq, Wk, Wv, wq_h, wk_h, wv_h,
        nullptr, nullptr, nullptr, Weff0, Weff1, Weff2);
    fold_wo<<<256, 256, 0, stream>>>(Wo, Woeff);

    // 2) projections: ph_z = x_z @ Weff_z + b_z   ([8192,1024]@[1024,64])
    gemm_n64_k1024<<<dim3(NROWS / 64, 3), 256, 0, stream>>>(
        query, key, value, Weff0, Weff1, Weff2,
        bq_h, bk_h, bv_h, ph, ph + 524288, ph + 1048576);

    // 3) causal single-head flash attention
    flash_attn<<<dim3(S_LEN / 32, BATCH), 256, 0, stream>>>(ph, oh);

    // 4) out = oh @ Woeff (head-tiling + Wo collapsed)
    epilogue<<<dim3(NROWS / 32, DMODEL / 128), 256, 0, stream>>>(oh, Woeff, out);
}

// Round 2
// 234.525 us; speedup vs baseline: 1.3704x; 1.3704x over previous
//
#include <hip/hip_runtime.h>
#include <math.h>

// Problem constants
#define S_LEN 2048
#define BATCH 4
#define DMODEL 1024
#define HDIM 64
#define NROWS (BATCH * S_LEN)   // 8192 flattened (b,s) rows

// ---------------------------------------------------------------------------
// Kernel 1a: generic skinny GEMM  C[M,64] = A[M,1024] @ B[1024,64] (+bias)
// ---------------------------------------------------------------------------
__global__ __launch_bounds__(256) void gemm_n64_k1024(
    const float* __restrict__ A0, const float* __restrict__ A1, const float* __restrict__ A2,
    const float* __restrict__ B0, const float* __restrict__ B1, const float* __restrict__ B2,
    const float* __restrict__ bias0, const float* __restrict__ bias1, const float* __restrict__ bias2,
    float* __restrict__ C0, float* __restrict__ C1, float* __restrict__ C2)
{
    const int z = blockIdx.y;
    const float* A    = (z == 0) ? A0 : (z == 1) ? A1 : A2;
    const float* B    = (z == 0) ? B0 : (z == 1) ? B1 : B2;
    const float* bias = (z == 0) ? bias0 : (z == 1) ? bias1 : bias2;
    float* C          = (z == 0) ? C0 : (z == 1) ? C1 : C2;

    __shared__ float As[64][65];
    __shared__ float Bs[64][64];

    const int t  = threadIdx.x;
    const int tr = t >> 4;
    const int tc = t & 15;
    const int r0 = blockIdx.x * 64;

    float acc[4][4] = {};

    for (int k0 = 0; k0 < 1024; k0 += 64) {
        __syncthreads();
        #pragma unroll
        for (int q = 0; q < 4; ++q) {
            int fid = t * 4 + q;
            int row = fid >> 4;
            int c4  = (fid & 15) << 2;
            float4 v = *reinterpret_cast<const float4*>(
                A + (size_t)(r0 + row) * 1024 + k0 + c4);
            As[row][c4 + 0] = v.x; As[row][c4 + 1] = v.y;
            As[row][c4 + 2] = v.z; As[row][c4 + 3] = v.w;
        }
        #pragma unroll
        for (int q = 0; q < 4; ++q) {
            int fid = t * 4 + q;
            int row = fid >> 4;
            int c4  = (fid & 15) << 2;
            float4 v = *reinterpret_cast<const float4*>(
                B + (size_t)(k0 + row) * 64 + c4);
            *reinterpret_cast<float4*>(&Bs[row][c4]) = v;
        }
        __syncthreads();

        #pragma unroll 4
        for (int kk = 0; kk < 64; ++kk) {
            float a[4], bb[4];
            #pragma unroll
            for (int i = 0; i < 4; ++i) a[i]  = As[4 * tr + i][kk];
            #pragma unroll
            for (int j = 0; j < 4; ++j) bb[j] = Bs[kk][4 * tc + j];
            #pragma unroll
            for (int i = 0; i < 4; ++i)
                #pragma unroll
                for (int j = 0; j < 4; ++j)
                    acc[i][j] += a[i] * bb[j];
        }
    }

    #pragma unroll
    for (int i = 0; i < 4; ++i)
        #pragma unroll
        for (int j = 0; j < 4; ++j) {
            float v = acc[i][j];
            if (bias) v += bias[4 * tc + j];
            C[(size_t)(r0 + 4 * tr + i) * 64 + 4 * tc + j] = v;
        }
}

// ---------------------------------------------------------------------------
// Kernel 1b: Wo_eff[j,e] = sum_h Wo[h*64+j, e]   (64 x 1024)
// ---------------------------------------------------------------------------
__global__ __launch_bounds__(256) void fold_wo(const float* __restrict__ Wo,
                                               float* __restrict__ Woeff)
{
    int idx = blockIdx.x * 256 + threadIdx.x;
    int j = idx >> 10;
    int e = idx & 1023;
    float s = 0.f;
    #pragma unroll
    for (int h = 0; h < 16; ++h)
        s += Wo[(size_t)((h << 6) + j) * 1024 + e];
    Woeff[idx] = s;
}

// ---------------------------------------------------------------------------
// Kernel 2a: split-KV causal flash attention partials.
// Grid: (288, B). Block 256 threads = one (q-tile of 32 rows, KV chunk of 256).
// Work per block <= 4 KV tiles of 64 -> load-balanced, 4.5 blocks/CU.
// Writes UNNORMALIZED partial O plus per-row (m, l) into scratch.
// Block decode: q-tile qt (0..63) has g+1 chunks where g = qt>>3.
//   group g occupies flat ids [4g(g+1), 4(g+1)(g+2)).
// ---------------------------------------------------------------------------
__global__ __launch_bounds__(256) void flash_attn_part(
    const float* __restrict__ ph, float* __restrict__ Opart,
    float* __restrict__ mpart, float* __restrict__ lpart)
{
    const int b = blockIdx.y;
    const int u = blockIdx.x;
    int g = 0;
    #pragma unroll
    for (int gg = 0; gg < 7; ++gg)
        if (u >= 4 * (gg + 1) * (gg + 2)) g = gg + 1;
    const int rem = u - 4 * g * (g + 1);
    const int d   = rem / (g + 1);
    const int c   = rem - d * (g + 1);          // chunk index within q-tile
    const int qt  = 8 * g + d;                  // q-tile index
    const int r0  = qt * 32;                    // first q row (within batch)
    const int slot = b * 288 + u;

    const size_t PHS = (size_t)BATCH * S_LEN * HDIM;
    const float* qh = ph + (size_t)b * S_LEN * HDIM;
    const float* kh = qh + PHS;
    const float* vh = qh + 2 * PHS;

    __shared__ float Qs[32][65];
    __shared__ float Ks[64][65];
    __shared__ float Vs[64][64];
    __shared__ float Ps[32][65];

    const int t  = threadIdx.x;
    const int tr = t >> 4;
    const int tc = t & 15;

    // stage Q tile (32 x 64)
    #pragma unroll
    for (int q = 0; q < 2; ++q) {
        int fid = t * 2 + q;
        int row = fid >> 4;
        int c4  = (fid & 15) << 2;
        float4 v = *reinterpret_cast<const float4*>(
            qh + (size_t)(r0 + row) * HDIM + c4);
        Qs[row][c4 + 0] = v.x; Qs[row][c4 + 1] = v.y;
        Qs[row][c4 + 2] = v.z; Qs[row][c4 + 3] = v.w;
    }

    float O[2][4] = {};
    float m[2] = {-INFINITY, -INFINITY};
    float l[2] = {0.f, 0.f};

    // tiles within this chunk; skip tiles entirely above the diagonal
    const int ntt = min(4, ((r0 + 31 - (c << 8)) >> 6) + 1);
    for (int tt = 0; tt < ntt; ++tt) {
        const int t0 = (c << 8) + (tt << 6);
        const bool domask = (t0 + 63 > r0);
        __syncthreads();
        #pragma unroll
        for (int q = 0; q < 4; ++q) {
            int fid = t * 4 + q;
            int row = fid >> 4;
            int c4  = (fid & 15) << 2;
            float4 kv = *reinterpret_cast<const float4*>(
                kh + (size_t)(t0 + row) * HDIM + c4);
            Ks[row][c4 + 0] = kv.x; Ks[row][c4 + 1] = kv.y;
            Ks[row][c4 + 2] = kv.z; Ks[row][c4 + 3] = kv.w;
            float4 vv = *reinterpret_cast<const float4*>(
                vh + (size_t)(t0 + row) * HDIM + c4);
            *reinterpret_cast<float4*>(&Vs[row][c4]) = vv;
        }
        __syncthreads();

        // S = Q K^T / 8
        float s[2][4] = {};
        #pragma unroll 4
        for (int kk = 0; kk < 64; ++kk) {
            float qv[2], kv[4];
            #pragma unroll
            for (int i = 0; i < 2; ++i) qv[i] = Qs[2 * tr + i][kk];
            #pragma unroll
            for (int j = 0; j < 4; ++j) kv[j] = Ks[4 * tc + j][kk];
            #pragma unroll
            for (int i = 0; i < 2; ++i)
                #pragma unroll
                for (int j = 0; j < 4; ++j)
                    s[i][j] += qv[i] * kv[j];
        }
        #pragma unroll
        for (int i = 0; i < 2; ++i)
            #pragma unroll
            for (int j = 0; j < 4; ++j) {
                s[i][j] *= 0.125f;
                if (domask) {
                    int col = t0 + 4 * tc + j;
                    int row = r0 + 2 * tr + i;
                    if (col > row) s[i][j] = -1e30f;
                }
            }

        // online softmax
        #pragma unroll
        for (int i = 0; i < 2; ++i) {
            float rm = fmaxf(fmaxf(s[i][0], s[i][1]), fmaxf(s[i][2], s[i][3]));
            rm = fmaxf(rm, __shfl_xor(rm, 1));
            rm = fmaxf(rm, __shfl_xor(rm, 2));
            rm = fmaxf(rm, __shfl_xor(rm, 4));
            rm = fmaxf(rm, __shfl_xor(rm, 8));
            float mn = fmaxf(m[i], rm);
            float sc = expf(m[i] - mn);
            float p[4];
            float rs = 0.f;
            #pragma unroll
            for (int j = 0; j < 4; ++j) { p[j] = expf(s[i][j] - mn); rs += p[j]; }
            rs += __shfl_xor(rs, 1);
            rs += __shfl_xor(rs, 2);
            rs += __shfl_xor(rs, 4);
            rs += __shfl_xor(rs, 8);
            l[i] = l[i] * sc + rs;
            m[i] = mn;
            #pragma unroll
            for (int j = 0; j < 4; ++j) O[i][j] *= sc;
            #pragma unroll
            for (int j = 0; j < 4; ++j) Ps[2 * tr + i][4 * tc + j] = p[j];
        }
        __syncthreads();

        // O += P V
        #pragma unroll 4
        for (int kk = 0; kk < 64; ++kk) {
            float pv[2], vv[4];
            #pragma unroll
            for (int i = 0; i < 2; ++i) pv[i] = Ps[2 * tr + i][kk];
            #pragma unroll
            for (int j = 0; j < 4; ++j) vv[j] = Vs[kk][4 * tc + j];
            #pragma unroll
            for (int i = 0; i < 2; ++i)
                #pragma unroll
                for (int j = 0; j < 4; ++j)
                    O[i][j] += pv[i] * vv[j];
        }
    }

    // write unnormalized partials
    #pragma unroll
    for (int i = 0; i < 2; ++i) {
        int row = 2 * tr + i;
        #pragma unroll
        for (int j = 0; j < 4; ++j)
            Opart[(size_t)slot * 2048 + row * 64 + 4 * tc + j] = O[i][j];
        if (tc == 0) {
            mpart[slot * 32 + row] = m[i];
            lpart[slot * 32 + row] = l[i];
        }
    }
}

// ---------------------------------------------------------------------------
// Kernel 2b: combine partials -> oh.  Grid (64, B), 256 threads.
// Thread t: row = t>>3, 8 cols at (t&7)*8.
// ---------------------------------------------------------------------------
__global__ __launch_bounds__(256) void flash_combine(
    const float* __restrict__ Opart, const float* __restrict__ mpart,
    const float* __restrict__ lpart, float* __restrict__ oh)
{
    const int qt = blockIdx.x, b = blockIdx.y;
    const int g  = qt >> 3;
    const int nc = g + 1;
    const int ubase = 4 * g * (g + 1) + (qt & 7) * (g + 1);
    const int t = threadIdx.x;
    const int row = t >> 3;
    const int c8  = (t & 7) << 3;

    float mc[8];
    float M = -INFINITY;
    #pragma unroll
    for (int c = 0; c < 8; ++c) {
        mc[c] = (c < nc) ? mpart[(b * 288 + ubase + c) * 32 + row] : -INFINITY;
        M = fmaxf(M, mc[c]);
    }
    float L = 0.f;
    float acc[8] = {};
    #pragma unroll
    for (int c = 0; c < 8; ++c) {
        if (c < nc) {
            const int slot = b * 288 + ubase + c;
            float w = expf(mc[c] - M);
            L += lpart[slot * 32 + row] * w;
            const float* op = Opart + (size_t)slot * 2048 + row * 64 + c8;
            float4 o1 = *reinterpret_cast<const float4*>(op);
            float4 o2 = *reinterpret_cast<const float4*>(op + 4);
            acc[0] += w * o1.x; acc[1] += w * o1.y;
            acc[2] += w * o1.z; acc[3] += w * o1.w;
            acc[4] += w * o2.x; acc[5] += w * o2.y;
            acc[6] += w * o2.z; acc[7] += w * o2.w;
        }
    }
    float inv = 1.f / L;
    float* dst = oh + ((size_t)b * S_LEN + qt * 32 + row) * HDIM + c8;
    float4 r1 = make_float4(acc[0] * inv, acc[1] * inv, acc[2] * inv, acc[3] * inv);
    float4 r2 = make_float4(acc[4] * inv, acc[5] * inv, acc[6] * inv, acc[7] * inv);
    *reinterpret_cast<float4*>(dst)     = r1;
    *reinterpret_cast<float4*>(dst + 4) = r2;
}

// ---------------------------------------------------------------------------
// Kernel 3: out[8192,1024] = oh[8192,64] @ Woeff[64,1024]
// ---------------------------------------------------------------------------
__global__ __launch_bounds__(256) void epilogue(const float* __restrict__ oh,
                                                const float* __restrict__ Woeff,
                                                float* __restrict__ out)
{
    const int r0 = blockIdx.x * 32;
    const int c0 = blockIdx.y * 128;
    const int t  = threadIdx.x;
    const int tr = t >> 5;
    const int tc = t & 31;

    __shared__ float OHs[32][65];
    __shared__ float Ws[64][128];

    #pragma unroll
    for (int q = 0; q < 2; ++q) {
        int fid = t * 2 + q;
        int row = fid >> 4;
        int c4  = (fid & 15) << 2;
        float4 v = *reinterpret_cast<const float4*>(
            oh + (size_t)(r0 + row) * HDIM + c4);
        OHs[row][c4 + 0] = v.x; OHs[row][c4 + 1] = v.y;
        OHs[row][c4 + 2] = v.z; OHs[row][c4 + 3] = v.w;
    }
    #pragma unroll
    for (int q = 0; q < 8; ++q) {
        int fid = t * 8 + q;
        int row = fid >> 5;
        int c4  = (fid & 31) << 2;
        float4 v = *reinterpret_cast<const float4*>(
            Woeff + (size_t)row * 1024 + c0 + c4);
        *reinterpret_cast<float4*>(&Ws[row][c4]) = v;
    }
    __syncthreads();

    float acc[4][4] = {};
    #pragma unroll 4
    for (int kk = 0; kk < 64; ++kk) {
        float a[4], w[4];
        #pragma unroll
        for (int i = 0; i < 4; ++i) a[i] = OHs[4 * tr + i][kk];
        #pragma unroll
        for (int j = 0; j < 4; ++j) w[j] = Ws[kk][tc + 32 * j];
        #pragma unroll
        for (int i = 0; i < 4; ++i)
            #pragma unroll
            for (int j = 0; j < 4; ++j)
                acc[i][j] += a[i] * w[j];
    }

    #pragma unroll
    for (int i = 0; i < 4; ++i)
        #pragma unroll
        for (int j = 0; j < 4; ++j)
            out[(size_t)(r0 + 4 * tr + i) * 1024 + c0 + tc + 32 * j] = acc[i][j];
}

// ---------------------------------------------------------------------------
extern "C" void kernel_launch(void* const* d_in, const int* in_sizes, int n_in,
                              void* d_out, int out_size, void* d_ws, size_t ws_size,
                              hipStream_t stream)
{
    const float* query = (const float*)d_in[0];
    const float* key   = (const float*)d_in[1];
    const float* value = (const float*)d_in[2];
    const float* Wq   = (const float*)d_in[4];
    const float* Wk   = (const float*)d_in[5];
    const float* Wv   = (const float*)d_in[6];
    const float* wq_h = (const float*)d_in[7];
    const float* bq_h = (const float*)d_in[8];
    const float* wk_h = (const float*)d_in[9];
    const float* bk_h = (const float*)d_in[10];
    const float* wv_h = (const float*)d_in[11];
    const float* bv_h = (const float*)d_in[12];
    const float* Wo   = (const float*)d_in[13];
    float* out = (float*)d_out;

    // workspace layout (floats): 9.44 MB
    float* ws    = (float*)d_ws;
    float* Weff0 = ws;                  // 1024*64
    float* Weff1 = ws + 65536;
    float* Weff2 = ws + 131072;
    float* Woeff = ws + 196608;         // 64*1024
    float* ph    = ws + 262144;         // 3 * 8192*64 (qh,kh,vh)
    float* oh    = ws + 1835008;        // 8192*64

    // partial buffers live in d_out (9.7 MB < 33.5 MB); epilogue overwrites all
    // of d_out afterwards, so this is safe and deterministic.
    float* Opart = out;                 // 1152 * 2048
    float* mpart = out + 2359296;       // 1152 * 32
    float* lpart = out + 2396160;       // 1152 * 32

    // 1) effective weights
    gemm_n64_k1024<<<dim3(16, 3), 256, 0, stream>>>(
        Wq, Wk, Wv, wq_h, wk_h, wv_h,
        nullptr, nullptr, nullptr, Weff0, Weff1, Weff2);
    fold_wo<<<256, 256, 0, stream>>>(Wo, Woeff);

    // 2) projections
    gemm_n64_k1024<<<dim3(NROWS / 64, 3), 256, 0, stream>>>(
        query, key, value, Weff0, Weff1, Weff2,
        bq_h, bk_h, bv_h, ph, ph + 524288, ph + 1048576);

    // 3) split-KV causal flash attention + combine
    flash_attn_part<<<dim3(288, BATCH), 256, 0, stream>>>(ph, Opart, mpart, lpart);
    flash_combine<<<dim3(S_LEN / 32, BATCH), 256, 0, stream>>>(Opart, mpart, lpart, oh);

    // 4) out = oh @ Woeff
    epilogue<<<dim3(NROWS / 32, DMODEL / 128), 256, 0, stream>>>(oh, Woeff, out);
}

// Round 3
// 118.901 us; speedup vs baseline: 2.7030x; 1.9724x over previous
//
#include <hip/hip_runtime.h>
#include <math.h>

#define S_LEN 2048
#define BATCH 4
#define DMODEL 1024
#define HDIM 64
#define NROWS (BATCH * S_LEN)   // 8192

typedef __attribute__((ext_vector_type(8))) short bf16x8;
typedef __attribute__((ext_vector_type(4))) float f32x4;

__device__ inline ushort f2bf(float f) {
    union { float f; uint u; } v{f};
    uint r = v.u + 0x7fffu + ((v.u >> 16) & 1u);   // RNE
    return (ushort)(r >> 16);
}

// ---------------------------------------------------------------------------
// Prep 1: WeffT_z[h][d] = (W_z @ w_h_z)[d][h] in bf16.  f32 VALU gemm (small).
// M=1024 rows of W, N=64, K=1024. Grid (16, 3).
// ---------------------------------------------------------------------------
__global__ __launch_bounds__(256) void prep_weff(
    const float* __restrict__ A0, const float* __restrict__ A1, const float* __restrict__ A2,
    const float* __restrict__ B0, const float* __restrict__ B1, const float* __restrict__ B2,
    ushort* __restrict__ T0, ushort* __restrict__ T1, ushort* __restrict__ T2)
{
    const int z = blockIdx.y;
    const float* A = (z == 0) ? A0 : (z == 1) ? A1 : A2;
    const float* B = (z == 0) ? B0 : (z == 1) ? B1 : B2;
    ushort* T      = (z == 0) ? T0 : (z == 1) ? T1 : T2;

    __shared__ float As[64][65];
    __shared__ float Bs[64][64];

    const int t  = threadIdx.x;
    const int tr = t >> 4;
    const int tc = t & 15;
    const int r0 = blockIdx.x * 64;

    float acc[4][4] = {};
    for (int k0 = 0; k0 < 1024; k0 += 64) {
        __syncthreads();
        #pragma unroll
        for (int q = 0; q < 4; ++q) {
            int fid = t * 4 + q;
            int row = fid >> 4;
            int c4  = (fid & 15) << 2;
            float4 v = *reinterpret_cast<const float4*>(
                A + (size_t)(r0 + row) * 1024 + k0 + c4);
            As[row][c4 + 0] = v.x; As[row][c4 + 1] = v.y;
            As[row][c4 + 2] = v.z; As[row][c4 + 3] = v.w;
        }
        #pragma unroll
        for (int q = 0; q < 4; ++q) {
            int fid = t * 4 + q;
            int row = fid >> 4;
            int c4  = (fid & 15) << 2;
            float4 v = *reinterpret_cast<const float4*>(
                B + (size_t)(k0 + row) * 64 + c4);
            *reinterpret_cast<float4*>(&Bs[row][c4]) = v;
        }
        __syncthreads();
        #pragma unroll 4
        for (int kk = 0; kk < 64; ++kk) {
            float a[4], bb[4];
            #pragma unroll
            for (int i = 0; i < 4; ++i) a[i]  = As[4 * tr + i][kk];
            #pragma unroll
            for (int j = 0; j < 4; ++j) bb[j] = Bs[kk][4 * tc + j];
            #pragma unroll
            for (int i = 0; i < 4; ++i)
                #pragma unroll
                for (int j = 0; j < 4; ++j)
                    acc[i][j] += a[i] * bb[j];
        }
    }
    // store transposed bf16: T[h][d], h = 4*tc+j, d = r0+4*tr+i
    #pragma unroll
    for (int i = 0; i < 4; ++i)
        #pragma unroll
        for (int j = 0; j < 4; ++j)
            T[(size_t)(4 * tc + j) * 1024 + (r0 + 4 * tr + i)] = f2bf(acc[i][j]);
}

// ---------------------------------------------------------------------------
// Prep 2: WoT[e][j] = sum_h Wo[h*64+j][e]  -> bf16 [1024][64]
// ---------------------------------------------------------------------------
__global__ __launch_bounds__(256) void fold_wo(const float* __restrict__ Wo,
                                               ushort* __restrict__ WoT)
{
    int idx = blockIdx.x * 256 + threadIdx.x;   // 0..65535
    int j = idx >> 10;
    int e = idx & 1023;
    float s = 0.f;
    #pragma unroll
    for (int h = 0; h < 16; ++h)
        s += Wo[(size_t)((h << 6) + j) * 1024 + e];
    WoT[(size_t)e * 64 + j] = f2bf(s);
}

// ---------------------------------------------------------------------------
// Projections (MFMA): ph_z[8192,64] = bf16(x_z[8192,1024] @ WeffT_z^T) + bias
// Grid (128, 3), 256 threads = 4 waves; wave w owns rows 16w..16w+15 of the
// 64-row block. BK=64 -> 16 k-iters, 8 MFMA each.
// ---------------------------------------------------------------------------
__global__ __launch_bounds__(256) void proj_mfma(
    const float* __restrict__ A0, const float* __restrict__ A1, const float* __restrict__ A2,
    const ushort* __restrict__ W0, const ushort* __restrict__ W1, const ushort* __restrict__ W2,
    const float* __restrict__ b0, const float* __restrict__ b1, const float* __restrict__ b2,
    ushort* __restrict__ O0, ushort* __restrict__ O1, ushort* __restrict__ O2)
{
    const int z = blockIdx.y;
    const float* A  = (z == 0) ? A0 : (z == 1) ? A1 : A2;
    const ushort* W = (z == 0) ? W0 : (z == 1) ? W1 : W2;
    const float* bias = (z == 0) ? b0 : (z == 1) ? b1 : b2;
    ushort* O       = (z == 0) ? O0 : (z == 1) ? O1 : O2;

    __shared__ ushort As[64][72];   // +8 pad: b128 frag reads ~2-way
    __shared__ ushort Bs[64][72];

    const int t    = threadIdx.x;
    const int w    = t >> 6;
    const int lane = t & 63;
    const int lg   = lane >> 4;
    const int lc   = lane & 15;
    const int r0   = blockIdx.x * 64;

    f32x4 acc[4] = {};

    for (int k0 = 0; k0 < 1024; k0 += 64) {
        __syncthreads();
        // A tile 64x64 f32 -> bf16 LDS
        #pragma unroll
        for (int q = 0; q < 4; ++q) {
            int u   = t * 4 + q;           // 0..1023 float4 units
            int row = u >> 4;
            int c4  = (u & 15) << 2;
            float4 v = *reinterpret_cast<const float4*>(
                A + (size_t)(r0 + row) * 1024 + k0 + c4);
            ushort4 p;
            p.x = f2bf(v.x); p.y = f2bf(v.y); p.z = f2bf(v.z); p.w = f2bf(v.w);
            *reinterpret_cast<ushort4*>(&As[row][c4]) = p;
        }
        // B tile: WeffT rows h=0..63, k-window [k0,k0+64)
        #pragma unroll
        for (int q = 0; q < 2; ++q) {
            int u   = t * 2 + q;           // 0..511 16B units
            int row = u >> 3;
            int c8  = (u & 7) << 3;
            uint4 v = *reinterpret_cast<const uint4*>(W + (size_t)row * 1024 + k0 + c8);
            *reinterpret_cast<uint4*>(&Bs[row][c8]) = v;
        }
        __syncthreads();

        bf16x8 af0 = *reinterpret_cast<const bf16x8*>(&As[16 * w + lc][lg * 8]);
        bf16x8 af1 = *reinterpret_cast<const bf16x8*>(&As[16 * w + lc][32 + lg * 8]);
        #pragma unroll
        for (int n = 0; n < 4; ++n) {
            bf16x8 bf0 = *reinterpret_cast<const bf16x8*>(&Bs[16 * n + lc][lg * 8]);
            bf16x8 bf1 = *reinterpret_cast<const bf16x8*>(&Bs[16 * n + lc][32 + lg * 8]);
            acc[n] = __builtin_amdgcn_mfma_f32_16x16x32_bf16(af0, bf0, acc[n], 0, 0, 0);
            acc[n] = __builtin_amdgcn_mfma_f32_16x16x32_bf16(af1, bf1, acc[n], 0, 0, 0);
        }
    }

    #pragma unroll
    for (int n = 0; n < 4; ++n) {
        float bv = bias[16 * n + lc];
        #pragma unroll
        for (int reg = 0; reg < 4; ++reg) {
            int row = r0 + 16 * w + 4 * lg + reg;
            O[(size_t)row * 64 + 16 * n + lc] = f2bf(acc[n][reg] + bv);
        }
    }
}

// ---------------------------------------------------------------------------
// V transpose: vh[b][s][64] bf16 -> vhT[b][64][2048] bf16.  Grid (32, 4).
// ---------------------------------------------------------------------------
__global__ __launch_bounds__(256) void transpose_v(const ushort* __restrict__ vh,
                                                   ushort* __restrict__ vhT)
{
    const int b  = blockIdx.y;
    const int r0 = blockIdx.x * 64;
    __shared__ ushort T[64][72];
    const int t = threadIdx.x;

    #pragma unroll
    for (int q = 0; q < 2; ++q) {
        int u  = t * 2 + q;
        int s  = u >> 3;
        int d8 = (u & 7) << 3;
        uint4 v = *reinterpret_cast<const uint4*>(
            vh + ((size_t)b * S_LEN + r0 + s) * 64 + d8);
        *reinterpret_cast<uint4*>(&T[s][d8]) = v;
    }
    __syncthreads();
    #pragma unroll
    for (int q = 0; q < 2; ++q) {
        int u  = t * 2 + q;
        int d  = u >> 3;
        int s8 = (u & 7) << 3;
        uint4 o;
        uint* ow = reinterpret_cast<uint*>(&o);
        #pragma unroll
        for (int i = 0; i < 4; ++i)
            ow[i] = (uint)T[s8 + 2 * i][d] | ((uint)T[s8 + 2 * i + 1][d] << 16);
        *reinterpret_cast<uint4*>(
            vhT + (size_t)b * 64 * S_LEN + (size_t)d * S_LEN + r0 + s8) = o;
    }
}

// ---------------------------------------------------------------------------
// Flash attention (MFMA, split-KV): block = 64 q-rows x 256-kv chunk.
// 4 waves; wave w owns q-rows 16w..16w+15 with private online softmax over
// up to 4 staged kv-64 tiles. Swapped QK^T: S^T = mfma(K, Q) -> q lane-local.
// Writes unnormalized partial O^T as Opart[slot][d][q] (f32) + m,l.
// Grid (144, 4). Block decode: group gi=qt>>2 occupies [2gi(gi+1), +4(gi+1)).
// ---------------------------------------------------------------------------
__global__ __launch_bounds__(256) void flash_mfma(
    const ushort* __restrict__ qh, const ushort* __restrict__ kh,
    const ushort* __restrict__ vhT,
    float* __restrict__ Opart, float* __restrict__ mpart, float* __restrict__ lpart)
{
    const int b = blockIdx.y;
    const int u = blockIdx.x;
    int gi = 0;
    #pragma unroll
    for (int gg = 0; gg < 7; ++gg)
        if (u >= 2 * (gg + 1) * (gg + 2)) gi = gg + 1;
    const int rem = u - 2 * gi * (gi + 1);
    const int dq  = rem / (gi + 1);
    const int c   = rem - dq * (gi + 1);
    const int qt  = 4 * gi + dq;
    const int r0  = qt * 64;
    const int kvbase = c << 8;
    const int slot = b * 144 + u;

    __shared__ ushort Qs[64][72];
    __shared__ ushort Ks[64][72];
    __shared__ ushort Vt[64][72];
    __shared__ ushort Pw[4][16][72];

    const int t    = threadIdx.x;
    const int w    = t >> 6;
    const int lane = t & 63;
    const int lg   = lane >> 4;
    const int lc   = lane & 15;

    const ushort* qb  = qh  + (size_t)b * S_LEN * 64;
    const ushort* kb  = kh  + (size_t)b * S_LEN * 64;
    const ushort* vtb = vhT + (size_t)b * 64 * S_LEN;

    // stage Q (64 x 64)
    #pragma unroll
    for (int q = 0; q < 2; ++q) {
        int uu  = t * 2 + q;
        int row = uu >> 3;
        int c8  = (uu & 7) << 3;
        *reinterpret_cast<uint4*>(&Qs[row][c8]) =
            *reinterpret_cast<const uint4*>(qb + (size_t)(r0 + row) * 64 + c8);
    }
    __syncthreads();
    bf16x8 qf0 = *reinterpret_cast<const bf16x8*>(&Qs[16 * w + lc][lg * 8]);
    bf16x8 qf1 = *reinterpret_cast<const bf16x8*>(&Qs[16 * w + lc][32 + lg * 8]);

    f32x4 od[4] = {};
    float m = -INFINITY, lsum = 0.f;
    const int qrow = r0 + 16 * w + lc;

    const int ntt = min(4, ((r0 + 63 - kvbase) >> 6) + 1);
    for (int tt = 0; tt < ntt; ++tt) {
        const int t0 = kvbase + (tt << 6);
        __syncthreads();
        // stage K tile (rows kv, cols d) and V^T tile (rows d, cols kv)
        #pragma unroll
        for (int q = 0; q < 2; ++q) {
            int uu  = t * 2 + q;
            int row = uu >> 3;
            int c8  = (uu & 7) << 3;
            *reinterpret_cast<uint4*>(&Ks[row][c8]) =
                *reinterpret_cast<const uint4*>(kb + (size_t)(t0 + row) * 64 + c8);
            *reinterpret_cast<uint4*>(&Vt[row][c8]) =
                *reinterpret_cast<const uint4*>(vtb + (size_t)row * S_LEN + t0 + c8);
        }
        __syncthreads();

        if (t0 <= r0 + 16 * w + 15) {   // tile not fully above this wave's rows
            // S^T[kv][q] = K · Q^T
            f32x4 s[4] = {};
            #pragma unroll
            for (int a = 0; a < 4; ++a) {
                bf16x8 kf0 = *reinterpret_cast<const bf16x8*>(&Ks[16 * a + lc][lg * 8]);
                bf16x8 kf1 = *reinterpret_cast<const bf16x8*>(&Ks[16 * a + lc][32 + lg * 8]);
                s[a] = __builtin_amdgcn_mfma_f32_16x16x32_bf16(kf0, qf0, s[a], 0, 0, 0);
                s[a] = __builtin_amdgcn_mfma_f32_16x16x32_bf16(kf1, qf1, s[a], 0, 0, 0);
            }
            // scale + causal mask + row max (row = q, lane-local)
            float rm = -1e30f;
            #pragma unroll
            for (int a = 0; a < 4; ++a)
                #pragma unroll
                for (int reg = 0; reg < 4; ++reg) {
                    int kv = t0 + 16 * a + 4 * lg + reg;
                    float v = s[a][reg] * 0.125f;
                    if (kv > qrow) v = -1e30f;
                    s[a][reg] = v;
                    rm = fmaxf(rm, v);
                }
            rm = fmaxf(rm, __shfl_xor(rm, 16));
            rm = fmaxf(rm, __shfl_xor(rm, 32));
            float mn = fmaxf(m, rm);
            float sc = __expf(m - mn);     // first tile: exp(-inf)=0
            float rs = 0.f;
            #pragma unroll
            for (int a = 0; a < 4; ++a)
                #pragma unroll
                for (int reg = 0; reg < 4; ++reg) {
                    float p = __expf(s[a][reg] - mn);
                    s[a][reg] = p;
                    rs += p;
                }
            rs += __shfl_xor(rs, 16);
            rs += __shfl_xor(rs, 32);
            lsum = lsum * sc + rs;
            m = mn;
            #pragma unroll
            for (int di = 0; di < 4; ++di) od[di] *= sc;

            // P -> LDS bf16 as P[q][kv] (wave-private buffer)
            #pragma unroll
            for (int a = 0; a < 4; ++a)
                #pragma unroll
                for (int rp = 0; rp < 2; ++rp) {
                    uint pk = (uint)f2bf(s[a][2 * rp]) |
                              ((uint)f2bf(s[a][2 * rp + 1]) << 16);
                    *reinterpret_cast<uint*>(&Pw[w][lc][16 * a + 4 * lg + 2 * rp]) = pk;
                }
            // O^T += V^T · P^T
            bf16x8 pf0 = *reinterpret_cast<const bf16x8*>(&Pw[w][lc][lg * 8]);
            bf16x8 pf1 = *reinterpret_cast<const bf16x8*>(&Pw[w][lc][32 + lg * 8]);
            #pragma unroll
            for (int di = 0; di < 4; ++di) {
                bf16x8 vf0 = *reinterpret_cast<const bf16x8*>(&Vt[16 * di + lc][lg * 8]);
                bf16x8 vf1 = *reinterpret_cast<const bf16x8*>(&Vt[16 * di + lc][32 + lg * 8]);
                od[di] = __builtin_amdgcn_mfma_f32_16x16x32_bf16(vf0, pf0, od[di], 0, 0, 0);
                od[di] = __builtin_amdgcn_mfma_f32_16x16x32_bf16(vf1, pf1, od[di], 0, 0, 0);
            }
        }
    }

    // store partial O^T as [d][q] (coalesced: 16 consecutive q per store)
    #pragma unroll
    for (int di = 0; di < 4; ++di)
        #pragma unroll
        for (int reg = 0; reg < 4; ++reg)
            Opart[(size_t)slot * 4096 + (16 * di + 4 * lg + reg) * 64 + 16 * w + lc] =
                od[di][reg];
    if (lg == 0) {
        mpart[slot * 64 + 16 * w + lc] = m;
        lpart[slot * 64 + 16 * w + lc] = lsum;
    }
}

// ---------------------------------------------------------------------------
// Combine partials -> oh bf16 [8192][64].  Grid (32, 4), 256 threads.
// ---------------------------------------------------------------------------
__global__ __launch_bounds__(256) void flash_combine(
    const float* __restrict__ Opart, const float* __restrict__ mpart,
    const float* __restrict__ lpart, ushort* __restrict__ oh)
{
    const int qt = blockIdx.x, b = blockIdx.y;
    const int gi = qt >> 2;
    const int nc = gi + 1;
    const int ubase = 2 * gi * (gi + 1) + (qt & 3) * (gi + 1);
    __shared__ float T[64][65];

    const int t  = threadIdx.x;
    const int q  = t & 63;
    const int d0 = (t >> 6) << 4;

    float mc[8];
    float M = -INFINITY;
    #pragma unroll
    for (int cc = 0; cc < 8; ++cc) {
        mc[cc] = (cc < nc) ? mpart[(b * 144 + ubase + cc) * 64 + q] : -INFINITY;
        M = fmaxf(M, mc[cc]);
    }
    float L = 0.f;
    float acc[16] = {};
    for (int cc = 0; cc < nc; ++cc) {
        const int slot = b * 144 + ubase + cc;
        float wgt = __expf(mc[cc] - M);
        L += lpart[slot * 64 + q] * wgt;
        const float* op = Opart + (size_t)slot * 4096 + q;
        #pragma unroll
        for (int i = 0; i < 16; ++i)
            acc[i] += wgt * op[(d0 + i) * 64];
    }
    float inv = 1.f / L;
    #pragma unroll
    for (int i = 0; i < 16; ++i) T[q][d0 + i] = acc[i] * inv;
    __syncthreads();

    const int q2 = t >> 2;
    const int ds = (t & 3) << 4;
    uint wbuf[8];
    #pragma unroll
    for (int i = 0; i < 8; ++i)
        wbuf[i] = (uint)f2bf(T[q2][ds + 2 * i]) |
                  ((uint)f2bf(T[q2][ds + 2 * i + 1]) << 16);
    ushort* dst = oh + ((size_t)b * S_LEN + qt * 64 + q2) * 64 + ds;
    uint4 o1, o2;
    o1.x = wbuf[0]; o1.y = wbuf[1]; o1.z = wbuf[2]; o1.w = wbuf[3];
    o2.x = wbuf[4]; o2.y = wbuf[5]; o2.z = wbuf[6]; o2.w = wbuf[7];
    *reinterpret_cast<uint4*>(dst)     = o1;
    *reinterpret_cast<uint4*>(dst + 8) = o2;
}

// ---------------------------------------------------------------------------
// Epilogue (MFMA): out[8192,1024] = oh[8192,64] @ WoT^T.  Grid (128, 8).
// ---------------------------------------------------------------------------
__global__ __launch_bounds__(256) void epilogue_mfma(
    const ushort* __restrict__ oh, const ushort* __restrict__ WoT,
    float* __restrict__ out)
{
    const int r0 = blockIdx.x * 64;
    const int c0 = blockIdx.y * 128;
    __shared__ ushort As[64][72];
    __shared__ ushort Bs[128][72];

    const int t    = threadIdx.x;
    const int w    = t >> 6;
    const int lane = t & 63;
    const int lg   = lane >> 4;
    const int lc   = lane & 15;

    #pragma unroll
    for (int q = 0; q < 2; ++q) {
        int u   = t * 2 + q;
        int row = u >> 3;
        int c8  = (u & 7) << 3;
        *reinterpret_cast<uint4*>(&As[row][c8]) =
            *reinterpret_cast<const uint4*>(oh + (size_t)(r0 + row) * 64 + c8);
    }
    #pragma unroll
    for (int q = 0; q < 4; ++q) {
        int u   = t * 4 + q;
        int row = u >> 3;               // 0..127
        int c8  = (u & 7) << 3;
        *reinterpret_cast<uint4*>(&Bs[row][c8]) =
            *reinterpret_cast<const uint4*>(WoT + (size_t)(c0 + row) * 64 + c8);
    }
    __syncthreads();

    bf16x8 af0 = *reinterpret_cast<const bf16x8*>(&As[16 * w + lc][lg * 8]);
    bf16x8 af1 = *reinterpret_cast<const bf16x8*>(&As[16 * w + lc][32 + lg * 8]);
    f32x4 acc[8] = {};
    #pragma unroll
    for (int n = 0; n < 8; ++n) {
        bf16x8 bf0 = *reinterpret_cast<const bf16x8*>(&Bs[16 * n + lc][lg * 8]);
        bf16x8 bf1 = *reinterpret_cast<const bf16x8*>(&Bs[16 * n + lc][32 + lg * 8]);
        acc[n] = __builtin_amdgcn_mfma_f32_16x16x32_bf16(af0, bf0, acc[n], 0, 0, 0);
        acc[n] = __builtin_amdgcn_mfma_f32_16x16x32_bf16(af1, bf1, acc[n], 0, 0, 0);
    }
    #pragma unroll
    for (int n = 0; n < 8; ++n)
        #pragma unroll
        for (int reg = 0; reg < 4; ++reg)
            out[(size_t)(r0 + 16 * w + 4 * lg + reg) * 1024 + c0 + 16 * n + lc] =
                acc[n][reg];
}

// ---------------------------------------------------------------------------
extern "C" void kernel_launch(void* const* d_in, const int* in_sizes, int n_in,
                              void* d_out, int out_size, void* d_ws, size_t ws_size,
                              hipStream_t stream)
{
    const float* query = (const float*)d_in[0];
    const float* key   = (const float*)d_in[1];
    const float* value = (const float*)d_in[2];
    const float* Wq   = (const float*)d_in[4];
    const float* Wk   = (const float*)d_in[5];
    const float* Wv   = (const float*)d_in[6];
    const float* wq_h = (const float*)d_in[7];
    const float* bq_h = (const float*)d_in[8];
    const float* wk_h = (const float*)d_in[9];
    const float* bk_h = (const float*)d_in[10];
    const float* wv_h = (const float*)d_in[11];
    const float* bv_h = (const float*)d_in[12];
    const float* Wo   = (const float*)d_in[13];
    float* out = (float*)d_out;

    // workspace (ushort): 5.77 MB
    ushort* W16  = (ushort*)d_ws;
    ushort* WT0  = W16;                 // 64*1024
    ushort* WT1  = W16 + 65536;
    ushort* WT2  = W16 + 131072;
    ushort* WoT  = W16 + 196608;        // 1024*64
    ushort* qh   = W16 + 262144;        // 8192*64 each
    ushort* kh   = qh + 524288;
    ushort* vh   = kh + 524288;
    ushort* vhT  = vh + 524288;
    ushort* oh   = vhT + 524288;

    // partials in d_out (9.7 MB < 33.5 MB); epilogue rewrites all of d_out.
    float* Opart = out;                 // 576 * 4096
    float* mpart = out + 2359296;       // 576 * 64
    float* lpart = out + 2396160;

    prep_weff<<<dim3(16, 3), 256, 0, stream>>>(
        Wq, Wk, Wv, wq_h, wk_h, wv_h, WT0, WT1, WT2);
    fold_wo<<<256, 256, 0, stream>>>(Wo, WoT);

    proj_mfma<<<dim3(NROWS / 64, 3), 256, 0, stream>>>(
        query, key, value, WT0, WT1, WT2, bq_h, bk_h, bv_h, qh, kh, vh);

    transpose_v<<<dim3(S_LEN / 64, BATCH), 256, 0, stream>>>(vh, vhT);

    flash_mfma<<<dim3(144, BATCH), 256, 0, stream>>>(
        qh, kh, vhT, Opart, mpart, lpart);
    flash_combine<<<dim3(S_LEN / 64, BATCH), 256, 0, stream>>>(
        Opart, mpart, lpart, oh);

    epilogue_mfma<<<dim3(NROWS / 64, DMODEL / 128), 256, 0, stream>>>(oh, WoT, out);
}

// Round 4
// 82.783 us; speedup vs baseline: 3.8824x; 1.4363x over previous
//
#include <hip/hip_runtime.h>
#include <math.h>

#define S_LEN 2048
#define BATCH 4
#define DMODEL 1024
#define HDIM 64
#define NROWS (BATCH * S_LEN)   // 8192

typedef __attribute__((ext_vector_type(8))) short bf16x8;
typedef __attribute__((ext_vector_type(4))) float f32x4;

__device__ inline ushort f2bf(float f) {
    union { float f; uint u; } v{f};
    uint r = v.u + 0x7fffu + ((v.u >> 16) & 1u);   // RNE
    return (ushort)(r >> 16);
}

// ---------------------------------------------------------------------------
// Prep 1 (MFMA): WeffT_z[h][d] = (W_z @ w_h_z)[d][h] in bf16.
// Grid (16, 3), 256 thr = 4 waves. Same fragment conventions as proj_mfma
// (validated in round 3): A-frag row=lc k=lg*8, B-frag col=lc, C row=4lg+reg.
// ---------------------------------------------------------------------------
__global__ __launch_bounds__(256) void prep_weff_mfma(
    const float* __restrict__ A0, const float* __restrict__ A1, const float* __restrict__ A2,
    const float* __restrict__ B0, const float* __restrict__ B1, const float* __restrict__ B2,
    ushort* __restrict__ T0, ushort* __restrict__ T1, ushort* __restrict__ T2)
{
    const int z = blockIdx.y;
    const float* A = (z == 0) ? A0 : (z == 1) ? A1 : A2;
    const float* B = (z == 0) ? B0 : (z == 1) ? B1 : B2;
    ushort* T      = (z == 0) ? T0 : (z == 1) ? T1 : T2;

    __shared__ ushort As[64][72];   // W rows (M) x k
    __shared__ ushort Bt[64][72];   // w_h transposed: [h][k]

    const int t    = threadIdx.x;
    const int w    = t >> 6;
    const int lane = t & 63;
    const int lg   = lane >> 4;
    const int lc   = lane & 15;
    const int r0   = blockIdx.x * 64;

    f32x4 acc[4] = {};

    for (int k0 = 0; k0 < 1024; k0 += 64) {
        __syncthreads();
        // stage A tile: W rows r0..r0+63, k window, f32 -> bf16
        #pragma unroll
        for (int q = 0; q < 4; ++q) {
            int u   = t * 4 + q;
            int row = u >> 4;
            int c4  = (u & 15) << 2;
            float4 v = *reinterpret_cast<const float4*>(
                A + (size_t)(r0 + row) * 1024 + k0 + c4);
            ushort4 p;
            p.x = f2bf(v.x); p.y = f2bf(v.y); p.z = f2bf(v.z); p.w = f2bf(v.w);
            *reinterpret_cast<ushort4*>(&As[row][c4]) = p;
        }
        // stage B transposed: Bt[h][k] <- w_h[k0+kr][h]
        #pragma unroll
        for (int q = 0; q < 4; ++q) {
            int u  = t * 4 + q;
            int kr = u >> 4;
            int h4 = (u & 15) << 2;
            float4 v = *reinterpret_cast<const float4*>(
                B + (size_t)(k0 + kr) * 64 + h4);
            Bt[h4 + 0][kr] = f2bf(v.x);
            Bt[h4 + 1][kr] = f2bf(v.y);
            Bt[h4 + 2][kr] = f2bf(v.z);
            Bt[h4 + 3][kr] = f2bf(v.w);
        }
        __syncthreads();

        bf16x8 af0 = *reinterpret_cast<const bf16x8*>(&As[16 * w + lc][lg * 8]);
        bf16x8 af1 = *reinterpret_cast<const bf16x8*>(&As[16 * w + lc][32 + lg * 8]);
        #pragma unroll
        for (int n = 0; n < 4; ++n) {
            bf16x8 bf0 = *reinterpret_cast<const bf16x8*>(&Bt[16 * n + lc][lg * 8]);
            bf16x8 bf1 = *reinterpret_cast<const bf16x8*>(&Bt[16 * n + lc][32 + lg * 8]);
            acc[n] = __builtin_amdgcn_mfma_f32_16x16x32_bf16(af0, bf0, acc[n], 0, 0, 0);
            acc[n] = __builtin_amdgcn_mfma_f32_16x16x32_bf16(af1, bf1, acc[n], 0, 0, 0);
        }
    }

    // store transposed: T[h][d], h = 16n+lc (col), d = r0+16w+4lg+reg (row)
    #pragma unroll
    for (int n = 0; n < 4; ++n)
        #pragma unroll
        for (int reg = 0; reg < 4; ++reg)
            T[(size_t)(16 * n + lc) * 1024 + r0 + 16 * w + 4 * lg + reg] =
                f2bf(acc[n][reg]);
}

// ---------------------------------------------------------------------------
// Prep 2: WoT[e][j] = sum_h Wo[h*64+j][e]  -> bf16 [1024][64]
// ---------------------------------------------------------------------------
__global__ __launch_bounds__(256) void fold_wo(const float* __restrict__ Wo,
                                               ushort* __restrict__ WoT)
{
    int idx = blockIdx.x * 256 + threadIdx.x;   // 0..65535
    int j = idx >> 10;
    int e = idx & 1023;
    float s = 0.f;
    #pragma unroll
    for (int h = 0; h < 16; ++h)
        s += Wo[(size_t)((h << 6) + j) * 1024 + e];
    WoT[(size_t)e * 64 + j] = f2bf(s);
}

// ---------------------------------------------------------------------------
// Projections (MFMA): ph_z[8192,64] = bf16(x_z[8192,1024] @ WeffT_z^T) + bias
// Grid (128, 3), 256 threads = 4 waves.
// ---------------------------------------------------------------------------
__global__ __launch_bounds__(256) void proj_mfma(
    const float* __restrict__ A0, const float* __restrict__ A1, const float* __restrict__ A2,
    const ushort* __restrict__ W0, const ushort* __restrict__ W1, const ushort* __restrict__ W2,
    const float* __restrict__ b0, const float* __restrict__ b1, const float* __restrict__ b2,
    ushort* __restrict__ O0, ushort* __restrict__ O1, ushort* __restrict__ O2)
{
    const int z = blockIdx.y;
    const float* A  = (z == 0) ? A0 : (z == 1) ? A1 : A2;
    const ushort* W = (z == 0) ? W0 : (z == 1) ? W1 : W2;
    const float* bias = (z == 0) ? b0 : (z == 1) ? b1 : b2;
    ushort* O       = (z == 0) ? O0 : (z == 1) ? O1 : O2;

    __shared__ ushort As[64][72];
    __shared__ ushort Bs[64][72];

    const int t    = threadIdx.x;
    const int w    = t >> 6;
    const int lane = t & 63;
    const int lg   = lane >> 4;
    const int lc   = lane & 15;
    const int r0   = blockIdx.x * 64;

    f32x4 acc[4] = {};

    for (int k0 = 0; k0 < 1024; k0 += 64) {
        __syncthreads();
        #pragma unroll
        for (int q = 0; q < 4; ++q) {
            int u   = t * 4 + q;
            int row = u >> 4;
            int c4  = (u & 15) << 2;
            float4 v = *reinterpret_cast<const float4*>(
                A + (size_t)(r0 + row) * 1024 + k0 + c4);
            ushort4 p;
            p.x = f2bf(v.x); p.y = f2bf(v.y); p.z = f2bf(v.z); p.w = f2bf(v.w);
            *reinterpret_cast<ushort4*>(&As[row][c4]) = p;
        }
        #pragma unroll
        for (int q = 0; q < 2; ++q) {
            int u   = t * 2 + q;
            int row = u >> 3;
            int c8  = (u & 7) << 3;
            uint4 v = *reinterpret_cast<const uint4*>(W + (size_t)row * 1024 + k0 + c8);
            *reinterpret_cast<uint4*>(&Bs[row][c8]) = v;
        }
        __syncthreads();

        bf16x8 af0 = *reinterpret_cast<const bf16x8*>(&As[16 * w + lc][lg * 8]);
        bf16x8 af1 = *reinterpret_cast<const bf16x8*>(&As[16 * w + lc][32 + lg * 8]);
        #pragma unroll
        for (int n = 0; n < 4; ++n) {
            bf16x8 bf0 = *reinterpret_cast<const bf16x8*>(&Bs[16 * n + lc][lg * 8]);
            bf16x8 bf1 = *reinterpret_cast<const bf16x8*>(&Bs[16 * n + lc][32 + lg * 8]);
            acc[n] = __builtin_amdgcn_mfma_f32_16x16x32_bf16(af0, bf0, acc[n], 0, 0, 0);
            acc[n] = __builtin_amdgcn_mfma_f32_16x16x32_bf16(af1, bf1, acc[n], 0, 0, 0);
        }
    }

    #pragma unroll
    for (int n = 0; n < 4; ++n) {
        float bv = bias[16 * n + lc];
        #pragma unroll
        for (int reg = 0; reg < 4; ++reg) {
            int row = r0 + 16 * w + 4 * lg + reg;
            O[(size_t)row * 64 + 16 * n + lc] = f2bf(acc[n][reg] + bv);
        }
    }
}

// ---------------------------------------------------------------------------
// V transpose: vh[b][s][64] bf16 -> vhT[b][64][2048] bf16.  Grid (32, 4).
// ---------------------------------------------------------------------------
__global__ __launch_bounds__(256) void transpose_v(const ushort* __restrict__ vh,
                                                   ushort* __restrict__ vhT)
{
    const int b  = blockIdx.y;
    const int r0 = blockIdx.x * 64;
    __shared__ ushort T[64][72];
    const int t = threadIdx.x;

    #pragma unroll
    for (int q = 0; q < 2; ++q) {
        int u  = t * 2 + q;
        int s  = u >> 3;
        int d8 = (u & 7) << 3;
        uint4 v = *reinterpret_cast<const uint4*>(
            vh + ((size_t)b * S_LEN + r0 + s) * 64 + d8);
        *reinterpret_cast<uint4*>(&T[s][d8]) = v;
    }
    __syncthreads();
    #pragma unroll
    for (int q = 0; q < 2; ++q) {
        int u  = t * 2 + q;
        int d  = u >> 3;
        int s8 = (u & 7) << 3;
        uint4 o;
        uint* ow = reinterpret_cast<uint*>(&o);
        #pragma unroll
        for (int i = 0; i < 4; ++i)
            ow[i] = (uint)T[s8 + 2 * i][d] | ((uint)T[s8 + 2 * i + 1][d] << 16);
        *reinterpret_cast<uint4*>(
            vhT + (size_t)b * 64 * S_LEN + (size_t)d * S_LEN + r0 + s8) = o;
    }
}

// ---------------------------------------------------------------------------
// Flash attention (MFMA, split-KV): block = 64 q-rows x 256-kv chunk.
// Grid (144, 4).
// ---------------------------------------------------------------------------
__global__ __launch_bounds__(256) void flash_mfma(
    const ushort* __restrict__ qh, const ushort* __restrict__ kh,
    const ushort* __restrict__ vhT,
    float* __restrict__ Opart, float* __restrict__ mpart, float* __restrict__ lpart)
{
    const int b = blockIdx.y;
    const int u = blockIdx.x;
    int gi = 0;
    #pragma unroll
    for (int gg = 0; gg < 7; ++gg)
        if (u >= 2 * (gg + 1) * (gg + 2)) gi = gg + 1;
    const int rem = u - 2 * gi * (gi + 1);
    const int dq  = rem / (gi + 1);
    const int c   = rem - dq * (gi + 1);
    const int qt  = 4 * gi + dq;
    const int r0  = qt * 64;
    const int kvbase = c << 8;
    const int slot = b * 144 + u;

    __shared__ ushort Qs[64][72];
    __shared__ ushort Ks[64][72];
    __shared__ ushort Vt[64][72];
    __shared__ ushort Pw[4][16][72];

    const int t    = threadIdx.x;
    const int w    = t >> 6;
    const int lane = t & 63;
    const int lg   = lane >> 4;
    const int lc   = lane & 15;

    const ushort* qb  = qh  + (size_t)b * S_LEN * 64;
    const ushort* kb  = kh  + (size_t)b * S_LEN * 64;
    const ushort* vtb = vhT + (size_t)b * 64 * S_LEN;

    #pragma unroll
    for (int q = 0; q < 2; ++q) {
        int uu  = t * 2 + q;
        int row = uu >> 3;
        int c8  = (uu & 7) << 3;
        *reinterpret_cast<uint4*>(&Qs[row][c8]) =
            *reinterpret_cast<const uint4*>(qb + (size_t)(r0 + row) * 64 + c8);
    }
    __syncthreads();
    bf16x8 qf0 = *reinterpret_cast<const bf16x8*>(&Qs[16 * w + lc][lg * 8]);
    bf16x8 qf1 = *reinterpret_cast<const bf16x8*>(&Qs[16 * w + lc][32 + lg * 8]);

    f32x4 od[4] = {};
    float m = -INFINITY, lsum = 0.f;
    const int qrow = r0 + 16 * w + lc;

    const int ntt = min(4, ((r0 + 63 - kvbase) >> 6) + 1);
    for (int tt = 0; tt < ntt; ++tt) {
        const int t0 = kvbase + (tt << 6);
        __syncthreads();
        #pragma unroll
        for (int q = 0; q < 2; ++q) {
            int uu  = t * 2 + q;
            int row = uu >> 3;
            int c8  = (uu & 7) << 3;
            *reinterpret_cast<uint4*>(&Ks[row][c8]) =
                *reinterpret_cast<const uint4*>(kb + (size_t)(t0 + row) * 64 + c8);
            *reinterpret_cast<uint4*>(&Vt[row][c8]) =
                *reinterpret_cast<const uint4*>(vtb + (size_t)row * S_LEN + t0 + c8);
        }
        __syncthreads();

        if (t0 <= r0 + 16 * w + 15) {
            f32x4 s[4] = {};
            #pragma unroll
            for (int a = 0; a < 4; ++a) {
                bf16x8 kf0 = *reinterpret_cast<const bf16x8*>(&Ks[16 * a + lc][lg * 8]);
                bf16x8 kf1 = *reinterpret_cast<const bf16x8*>(&Ks[16 * a + lc][32 + lg * 8]);
                s[a] = __builtin_amdgcn_mfma_f32_16x16x32_bf16(kf0, qf0, s[a], 0, 0, 0);
                s[a] = __builtin_amdgcn_mfma_f32_16x16x32_bf16(kf1, qf1, s[a], 0, 0, 0);
            }
            float rm = -1e30f;
            #pragma unroll
            for (int a = 0; a < 4; ++a)
                #pragma unroll
                for (int reg = 0; reg < 4; ++reg) {
                    int kv = t0 + 16 * a + 4 * lg + reg;
                    float v = s[a][reg] * 0.125f;
                    if (kv > qrow) v = -1e30f;
                    s[a][reg] = v;
                    rm = fmaxf(rm, v);
                }
            rm = fmaxf(rm, __shfl_xor(rm, 16));
            rm = fmaxf(rm, __shfl_xor(rm, 32));
            float mn = fmaxf(m, rm);
            float sc = __expf(m - mn);
            float rs = 0.f;
            #pragma unroll
            for (int a = 0; a < 4; ++a)
                #pragma unroll
                for (int reg = 0; reg < 4; ++reg) {
                    float p = __expf(s[a][reg] - mn);
                    s[a][reg] = p;
                    rs += p;
                }
            rs += __shfl_xor(rs, 16);
            rs += __shfl_xor(rs, 32);
            lsum = lsum * sc + rs;
            m = mn;
            #pragma unroll
            for (int di = 0; di < 4; ++di) od[di] *= sc;

            #pragma unroll
            for (int a = 0; a < 4; ++a)
                #pragma unroll
                for (int rp = 0; rp < 2; ++rp) {
                    uint pk = (uint)f2bf(s[a][2 * rp]) |
                              ((uint)f2bf(s[a][2 * rp + 1]) << 16);
                    *reinterpret_cast<uint*>(&Pw[w][lc][16 * a + 4 * lg + 2 * rp]) = pk;
                }
            bf16x8 pf0 = *reinterpret_cast<const bf16x8*>(&Pw[w][lc][lg * 8]);
            bf16x8 pf1 = *reinterpret_cast<const bf16x8*>(&Pw[w][lc][32 + lg * 8]);
            #pragma unroll
            for (int di = 0; di < 4; ++di) {
                bf16x8 vf0 = *reinterpret_cast<const bf16x8*>(&Vt[16 * di + lc][lg * 8]);
                bf16x8 vf1 = *reinterpret_cast<const bf16x8*>(&Vt[16 * di + lc][32 + lg * 8]);
                od[di] = __builtin_amdgcn_mfma_f32_16x16x32_bf16(vf0, pf0, od[di], 0, 0, 0);
                od[di] = __builtin_amdgcn_mfma_f32_16x16x32_bf16(vf1, pf1, od[di], 0, 0, 0);
            }
        }
    }

    #pragma unroll
    for (int di = 0; di < 4; ++di)
        #pragma unroll
        for (int reg = 0; reg < 4; ++reg)
            Opart[(size_t)slot * 4096 + (16 * di + 4 * lg + reg) * 64 + 16 * w + lc] =
                od[di][reg];
    if (lg == 0) {
        mpart[slot * 64 + 16 * w + lc] = m;
        lpart[slot * 64 + 16 * w + lc] = lsum;
    }
}

// ---------------------------------------------------------------------------
// Combine partials -> oh bf16 [8192][64].  Grid (32, 4), 256 threads.
// ---------------------------------------------------------------------------
__global__ __launch_bounds__(256) void flash_combine(
    const float* __restrict__ Opart, const float* __restrict__ mpart,
    const float* __restrict__ lpart, ushort* __restrict__ oh)
{
    const int qt = blockIdx.x, b = blockIdx.y;
    const int gi = qt >> 2;
    const int nc = gi + 1;
    const int ubase = 2 * gi * (gi + 1) + (qt & 3) * (gi + 1);
    __shared__ float T[64][65];

    const int t  = threadIdx.x;
    const int q  = t & 63;
    const int d0 = (t >> 6) << 4;

    float mc[8];
    float M = -INFINITY;
    #pragma unroll
    for (int cc = 0; cc < 8; ++cc) {
        mc[cc] = (cc < nc) ? mpart[(b * 144 + ubase + cc) * 64 + q] : -INFINITY;
        M = fmaxf(M, mc[cc]);
    }
    float L = 0.f;
    float acc[16] = {};
    for (int cc = 0; cc < nc; ++cc) {
        const int slot = b * 144 + ubase + cc;
        float wgt = __expf(mc[cc] - M);
        L += lpart[slot * 64 + q] * wgt;
        const float* op = Opart + (size_t)slot * 4096 + q;
        #pragma unroll
        for (int i = 0; i < 16; ++i)
            acc[i] += wgt * op[(d0 + i) * 64];
    }
    float inv = 1.f / L;
    #pragma unroll
    for (int i = 0; i < 16; ++i) T[q][d0 + i] = acc[i] * inv;
    __syncthreads();

    const int q2 = t >> 2;
    const int ds = (t & 3) << 4;
    uint wbuf[8];
    #pragma unroll
    for (int i = 0; i < 8; ++i)
        wbuf[i] = (uint)f2bf(T[q2][ds + 2 * i]) |
                  ((uint)f2bf(T[q2][ds + 2 * i + 1]) << 16);
    ushort* dst = oh + ((size_t)b * S_LEN + qt * 64 + q2) * 64 + ds;
    uint4 o1, o2;
    o1.x = wbuf[0]; o1.y = wbuf[1]; o1.z = wbuf[2]; o1.w = wbuf[3];
    o2.x = wbuf[4]; o2.y = wbuf[5]; o2.z = wbuf[6]; o2.w = wbuf[7];
    *reinterpret_cast<uint4*>(dst)     = o1;
    *reinterpret_cast<uint4*>(dst + 8) = o2;
}

// ---------------------------------------------------------------------------
// Epilogue (MFMA): out[8192,1024] = oh[8192,64] @ WoT^T.  Grid (128, 8).
// ---------------------------------------------------------------------------
__global__ __launch_bounds__(256) void epilogue_mfma(
    const ushort* __restrict__ oh, const ushort* __restrict__ WoT,
    float* __restrict__ out)
{
    const int r0 = blockIdx.x * 64;
    const int c0 = blockIdx.y * 128;
    __shared__ ushort As[64][72];
    __shared__ ushort Bs[128][72];

    const int t    = threadIdx.x;
    const int w    = t >> 6;
    const int lane = t & 63;
    const int lg   = lane >> 4;
    const int lc   = lane & 15;

    #pragma unroll
    for (int q = 0; q < 2; ++q) {
        int u   = t * 2 + q;
        int row = u >> 3;
        int c8  = (u & 7) << 3;
        *reinterpret_cast<uint4*>(&As[row][c8]) =
            *reinterpret_cast<const uint4*>(oh + (size_t)(r0 + row) * 64 + c8);
    }
    #pragma unroll
    for (int q = 0; q < 4; ++q) {
        int u   = t * 4 + q;
        int row = u >> 3;
        int c8  = (u & 7) << 3;
        *reinterpret_cast<uint4*>(&Bs[row][c8]) =
            *reinterpret_cast<const uint4*>(WoT + (size_t)(c0 + row) * 64 + c8);
    }
    __syncthreads();

    bf16x8 af0 = *reinterpret_cast<const bf16x8*>(&As[16 * w + lc][lg * 8]);
    bf16x8 af1 = *reinterpret_cast<const bf16x8*>(&As[16 * w + lc][32 + lg * 8]);
    f32x4 acc[8] = {};
    #pragma unroll
    for (int n = 0; n < 8; ++n) {
        bf16x8 bf0 = *reinterpret_cast<const bf16x8*>(&Bs[16 * n + lc][lg * 8]);
        bf16x8 bf1 = *reinterpret_cast<const bf16x8*>(&Bs[16 * n + lc][32 + lg * 8]);
        acc[n] = __builtin_amdgcn_mfma_f32_16x16x32_bf16(af0, bf0, acc[n], 0, 0, 0);
        acc[n] = __builtin_amdgcn_mfma_f32_16x16x32_bf16(af1, bf1, acc[n], 0, 0, 0);
    }
    #pragma unroll
    for (int n = 0; n < 8; ++n)
        #pragma unroll
        for (int reg = 0; reg < 4; ++reg)
            out[(size_t)(r0 + 16 * w + 4 * lg + reg) * 1024 + c0 + 16 * n + lc] =
                acc[n][reg];
}

// ---------------------------------------------------------------------------
extern "C" void kernel_launch(void* const* d_in, const int* in_sizes, int n_in,
                              void* d_out, int out_size, void* d_ws, size_t ws_size,
                              hipStream_t stream)
{
    const float* query = (const float*)d_in[0];
    const float* key   = (const float*)d_in[1];
    const float* value = (const float*)d_in[2];
    const float* Wq   = (const float*)d_in[4];
    const float* Wk   = (const float*)d_in[5];
    const float* Wv   = (const float*)d_in[6];
    const float* wq_h = (const float*)d_in[7];
    const float* bq_h = (const float*)d_in[8];
    const float* wk_h = (const float*)d_in[9];
    const float* bk_h = (const float*)d_in[10];
    const float* wv_h = (const float*)d_in[11];
    const float* bv_h = (const float*)d_in[12];
    const float* Wo   = (const float*)d_in[13];
    float* out = (float*)d_out;

    // workspace (ushort): 5.77 MB
    ushort* W16  = (ushort*)d_ws;
    ushort* WT0  = W16;                 // 64*1024
    ushort* WT1  = W16 + 65536;
    ushort* WT2  = W16 + 131072;
    ushort* WoT  = W16 + 196608;        // 1024*64
    ushort* qh   = W16 + 262144;        // 8192*64 each
    ushort* kh   = qh + 524288;
    ushort* vh   = kh + 524288;
    ushort* vhT  = vh + 524288;
    ushort* oh   = vhT + 524288;

    // partials in d_out (9.7 MB < 33.5 MB); epilogue rewrites all of d_out.
    float* Opart = out;                 // 576 * 4096
    float* mpart = out + 2359296;       // 576 * 64
    float* lpart = out + 2396160;

    prep_weff_mfma<<<dim3(16, 3), 256, 0, stream>>>(
        Wq, Wk, Wv, wq_h, wk_h, wv_h, WT0, WT1, WT2);
    fold_wo<<<256, 256, 0, stream>>>(Wo, WoT);

    proj_mfma<<<dim3(NROWS / 64, 3), 256, 0, stream>>>(
        query, key, value, WT0, WT1, WT2, bq_h, bk_h, bv_h, qh, kh, vh);

    transpose_v<<<dim3(S_LEN / 64, BATCH), 256, 0, stream>>>(vh, vhT);

    flash_mfma<<<dim3(144, BATCH), 256, 0, stream>>>(
        qh, kh, vhT, Opart, mpart, lpart);
    flash_combine<<<dim3(S_LEN / 64, BATCH), 256, 0, stream>>>(
        Opart, mpart, lpart, oh);

    epilogue_mfma<<<dim3(NROWS / 64, DMODEL / 128), 256, 0, stream>>>(oh, WoT, out);
}